// Round 4
// baseline (15.884 us; speedup 1.0000x reference)
//
#include <hip/hip_runtime.h>

#define D_DIM 32768
#define NT 64
#define NKEYS 120
#define RS 4                 // row-split groups
#define CHUNK 128            // dims per chunk
#define K1_TPB 512
#define K1_WAVES 8

__constant__ int c_feat_idx[NKEYS] = {
    557, 581, 553, 551, 92, 554, 579, 570, 573, 577,
    565, 286, 555, 549, 13, 550, 63, 580, 556, 564,
    0, 576, 567, 552, 578, 588, 597, 566, 571, 44,
    572, 574, 14, 582, 381, 594, 4, 593, 218, 25,
    84, 592, 3, 591, 547, 561, 562, 548, 319, 596,
    558, 563, 87, 65, 599, 17, 88, 2, 49, 309,
    6, 81, 15, 590, 589, 43, 273, 420, 546, 568,
    400, 277, 202, 287, 434, 435, 423, 431, 301, 417,
    412, 205, 179, 327, 176, 442, 172, 450, 391, 163,
    154, 480, 485, 490, 491, 498, 503, 507, 509, 452,
    239, 388, 219, 303, 292, 310, 316, 320, 322, 324,
    326, 330, 336, 263, 262, 339, 340, 256, 345, 347};

__device__ __forceinline__ int level_idx(float x) {
    // replicate: clip(x,-5,5); round(((x+5)/10)*2047) half-to-even; clip 0..2047
    x = fminf(fmaxf(x, -5.0f), 5.0f);
    float v = (x + 5.0f) / 10.0f * 2047.0f;
    int i = (int)rintf(v);
    return min(max(i, 0), 2047);
}

// K1: grid = 256 chunks x 4 row-groups = 1024 blocks, 512 threads (8 waves).
// 4 blocks/CU x 8 waves = 32 waves/CU. VGPR <= 64 via launch_bounds(512,8).
// Each wave: 2 timestamps (8 row gathers) + <=4 keys (4 gathers), float2/lane.
__global__ __launch_bounds__(K1_TPB, 8) void hdc_partial_kernel(
    const float* __restrict__ input,
    const float* __restrict__ feat,
    const float* __restrict__ Wx,
    const float* __restrict__ Wy,
    const float* __restrict__ Wz,
    const float* __restrict__ Wt,
    const float* __restrict__ keys,
    int*   __restrict__ ws_m,
    float* __restrict__ ws_f)
{
    __shared__ int   s_meta[K1_WAVES][CHUNK];
    __shared__ float s_f[K1_WAVES][CHUNK];

    const int tid   = threadIdx.x;
    const int wave  = __builtin_amdgcn_readfirstlane(tid >> 6);  // 0..7
    const int lane  = tid & 63;
    const int chunk = blockIdx.x >> 2;     // 0..255
    const int rg    = blockIdx.x & 3;      // 0..3
    const int d0    = chunk * CHUNK + lane * 2;

    // ---- wave-uniform scalar index computation (no LDS, no barrier) ----
    const int t0 = rg * 16 + wave * 2;
    int rx[2], ry[2], rz[2], rt[2];
#pragma unroll
    for (int k = 0; k < 2; ++k) {
        int t = t0 + k;
        rx[k] = __builtin_amdgcn_readfirstlane(level_idx(input[t * 4 + 1]));
        ry[k] = __builtin_amdgcn_readfirstlane(level_idx(input[t * 4 + 2]));
        rz[k] = __builtin_amdgcn_readfirstlane(level_idx(input[t * 4 + 3]));
        int it = (int)rintf((float)t / 64.0f * 63.0f);
        rt[k] = __builtin_amdgcn_readfirstlane(min(max(it, 0), NT - 1));
    }
    const int nk = (wave < 6) ? 4 : 3;                       // 6*4 + 2*3 = 30 keys/rgroup
    const int j0 = rg * 30 + ((wave < 6) ? wave * 4 : 24 + (wave - 6) * 3);

    // ---- sample part: 2 timestamps ----
    unsigned sg0 = 0u, sg1 = 0u;
    int a30 = 0, a31 = 0;
#pragma unroll
    for (int k = 0; k < 2; ++k) {
        float2 x = *(const float2*)(Wx + ((size_t)rx[k] << 15) + d0);
        float2 y = *(const float2*)(Wy + ((size_t)ry[k] << 15) + d0);
        float2 z = *(const float2*)(Wz + ((size_t)rz[k] << 15) + d0);
        float2 w = *(const float2*)(Wt + ((size_t)rt[k] << 15) + d0);
        float sA = x.x + y.x + z.x;          // in {+-1, +-3} exactly
        float sB = x.y + y.y + z.y;
        sg0 ^= __float_as_uint(sA * w.x);
        sg1 ^= __float_as_uint(sB * w.y);
        a30 += (fabsf(sA) > 2.0f) ? 1 : 0;
        a31 += (fabsf(sB) > 2.0f) ? 1 : 0;
    }

    // ---- feature part: <=4 keys ----
    float f0 = 0.0f, f1 = 0.0f;
#pragma unroll
    for (int k = 0; k < 4; ++k) {
        if (k < nk) {
            int j = j0 + k;
            float fv = feat[c_feat_idx[j]];
            fv = fminf(fmaxf(fv, -1.0f), 1.0f);
            int fx = __builtin_amdgcn_readfirstlane((int)rintf((fv + 1.0f) * 0.5f * 32768.0f));
            float2 kv = *(const float2*)(keys + ((size_t)j << 15) + d0);
            f0 += (d0 < fx)     ? kv.x : -kv.x;
            f1 += (d0 + 1 < fx) ? kv.y : -kv.y;
        }
    }

    const int col = lane * 2;
    s_meta[wave][col]     = (int)(sg0 >> 31) | (a30 << 8);
    s_meta[wave][col + 1] = (int)(sg1 >> 31) | (a31 << 8);
    s_f[wave][col]     = f0;
    s_f[wave][col + 1] = f1;
    __syncthreads();

    if (tid < CHUNK) {
        int msum = 0;
        float f = 0.0f;
#pragma unroll
        for (int w2 = 0; w2 < K1_WAVES; ++w2) {
            msum += s_meta[w2][tid];
            f    += s_f[w2][tid];            // exact: sum of +-1 integers
        }
        int d = chunk * CHUNK + tid;
        ws_m[rg * D_DIM + d] = msum;
        ws_f[rg * D_DIM + d] = f;
    }
}

// K2: combine 4 partials per dim, decide sign. 128 blocks x 256 threads.
__global__ __launch_bounds__(256) void hdc_combine_kernel(
    const int*   __restrict__ ws_m,
    const float* __restrict__ ws_f,
    float* __restrict__ out)
{
    int d = blockIdx.x * 256 + threadIdx.x;
    int m = ws_m[d] + ws_m[D_DIM + d] + ws_m[2 * D_DIM + d] + ws_m[3 * D_DIM + d];
    float f = ws_f[d] + ws_f[D_DIM + d] + ws_f[2 * D_DIM + d] + ws_f[3 * D_DIM + d];
    bool neg  = (m & 1) != 0;        // parity of sign bits = sign of 64-fold product
    bool any3 = (m >> 8) != 0;       // any |x+y+z| == 3  (low byte <= 32, no carry)
    float o;
    if (f >= 0.0f) o = neg ? -1.0f : 1.0f;
    else           o = (neg && any3) ? 1.0f : -1.0f;
    out[d] = o;
}

extern "C" void kernel_launch(void* const* d_in, const int* in_sizes, int n_in,
                              void* d_out, int out_size, void* d_ws, size_t ws_size,
                              hipStream_t stream) {
    const float* input = (const float*)d_in[0];
    const float* feat  = (const float*)d_in[1];
    const float* Wx    = (const float*)d_in[2];
    const float* Wy    = (const float*)d_in[3];
    const float* Wz    = (const float*)d_in[4];
    const float* Wt    = (const float*)d_in[5];
    const float* keys  = (const float*)d_in[6];
    float* out = (float*)d_out;

    int*   ws_m = (int*)d_ws;                                  // RS * 32768 ints  (512 KB)
    float* ws_f = (float*)((char*)d_ws + (size_t)RS * D_DIM * 4); // RS * 32768 floats (512 KB)

    dim3 grid1(D_DIM / CHUNK * RS);   // 1024 blocks
    dim3 block1(K1_TPB);
    hipLaunchKernelGGL(hdc_partial_kernel, grid1, block1, 0, stream,
                       input, feat, Wx, Wy, Wz, Wt, keys, ws_m, ws_f);

    dim3 grid2(D_DIM / 256);          // 128 blocks
    dim3 block2(256);
    hipLaunchKernelGGL(hdc_combine_kernel, grid2, block2, 0, stream,
                       ws_m, ws_f, out);
}

// Round 5
// 14.726 us; speedup vs baseline: 1.0786x; 1.0786x over previous
//
#include <hip/hip_runtime.h>

#define D_DIM 32768
#define NT 64
#define NKEYS 120
#define TPB 1024
#define DB 128      // dims per block
#define NW 16       // waves per block

__constant__ int c_feat_idx[NKEYS] = {
    557, 581, 553, 551, 92, 554, 579, 570, 573, 577,
    565, 286, 555, 549, 13, 550, 63, 580, 556, 564,
    0, 576, 567, 552, 578, 588, 597, 566, 571, 44,
    572, 574, 14, 582, 381, 594, 4, 593, 218, 25,
    84, 592, 3, 591, 547, 561, 562, 548, 319, 596,
    558, 563, 87, 65, 599, 17, 88, 2, 49, 309,
    6, 81, 15, 590, 589, 43, 273, 420, 546, 568,
    400, 277, 202, 287, 434, 435, 423, 431, 301, 417,
    412, 205, 179, 327, 176, 442, 172, 450, 391, 163,
    154, 480, 485, 490, 491, 498, 503, 507, 509, 452,
    239, 388, 219, 303, 292, 310, 316, 320, 322, 324,
    326, 330, 336, 263, 262, 339, 340, 256, 345, 347};

__device__ __forceinline__ int level_idx(float x) {
    // replicate: clip(x,-5,5); round(((x+5)/10)*2047) half-to-even; clip 0..2047
    x = fminf(fmaxf(x, -5.0f), 5.0f);
    float v = (x + 5.0f) / 10.0f * 2047.0f;
    int i = (int)rintf(v);
    return min(max(i, 0), 2047);
}

__global__ __launch_bounds__(TPB) void hdc_encode_kernel(
    const float* __restrict__ input,
    const float* __restrict__ feat,
    const float* __restrict__ Wx,
    const float* __restrict__ Wy,
    const float* __restrict__ Wz,
    const float* __restrict__ Wt,
    const float* __restrict__ keys,
    float* __restrict__ out)
{
    __shared__ int   s_meta[NW][DB];
    __shared__ float s_f[NW][DB];

    const int tid  = threadIdx.x;
    const int wave = __builtin_amdgcn_readfirstlane(tid >> 6);  // 0..15, SGPR
    const int lane = tid & 63;
    const int dloc = lane * 2;                    // dim offset within chunk
    const int d0   = blockIdx.x * DB + dloc;      // global dim (lane's first)

    // ---- barrier-free wave-uniform scalar prologue ----
    // 4 timestamps -> 16 row base pointers (SGPR pairs)
    const float* bx[4]; const float* by[4]; const float* bz[4]; const float* bt[4];
#pragma unroll
    for (int k = 0; k < 4; ++k) {
        int t = wave * 4 + k;                     // uniform
        int rx = __builtin_amdgcn_readfirstlane(level_idx(input[t * 4 + 1]));
        int ry = __builtin_amdgcn_readfirstlane(level_idx(input[t * 4 + 2]));
        int rz = __builtin_amdgcn_readfirstlane(level_idx(input[t * 4 + 3]));
        int it = (int)rintf((float)t / 64.0f * 63.0f);
        it = __builtin_amdgcn_readfirstlane(min(max(it, 0), NT - 1));
        bx[k] = Wx + ((size_t)rx << 15);
        by[k] = Wy + ((size_t)ry << 15);
        bz[k] = Wz + ((size_t)rz << 15);
        bt[k] = Wt + ((size_t)it << 15);
    }
    // <=8 keys: thresholds (SGPR) + base pointers (SGPR pairs)
    const int nk = (wave < 8) ? 8 : 7;            // 8*8 + 8*7 = 120
    const int j0 = (wave < 8) ? wave * 8 : 64 + (wave - 8) * 7;
    int fx[8]; const float* bk[8];
#pragma unroll
    for (int k = 0; k < 8; ++k) {
        int j = j0 + ((k < nk) ? k : 0);          // clamp: duplicate j0 for pad lanes
        float fv = feat[c_feat_idx[j]];
        fv = fminf(fmaxf(fv, -1.0f), 1.0f);
        fx[k] = __builtin_amdgcn_readfirstlane((int)rintf((fv + 1.0f) * 0.5f * 32768.0f));
        bk[k] = keys + ((size_t)j << 15);
    }

    // ---- issue ALL gathers back-to-back (shared voffset, SGPR bases) ----
    float2 sx[4], sy[4], sz[4], st[4];
#pragma unroll
    for (int k = 0; k < 4; ++k) {
        sx[k] = *(const float2*)(bx[k] + d0);
        sy[k] = *(const float2*)(by[k] + d0);
        sz[k] = *(const float2*)(bz[k] + d0);
        st[k] = *(const float2*)(bt[k] + d0);
    }
    float2 kv[8];
#pragma unroll
    for (int k = 0; k < 8; ++k) {
        kv[k] = *(const float2*)(bk[k] + d0);
    }

    // ---- consume in issue order ----
    unsigned sg0 = 0u, sg1 = 0u;
    int a30 = 0, a31 = 0;
#pragma unroll
    for (int k = 0; k < 4; ++k) {
        float sA = sx[k].x + sy[k].x + sz[k].x;   // in {+-1, +-3} exactly
        float sB = sx[k].y + sy[k].y + sz[k].y;
        sg0 ^= __float_as_uint(sA * st[k].x);
        sg1 ^= __float_as_uint(sB * st[k].y);
        a30 |= (fabsf(sA) > 2.0f) ? 1 : 0;
        a31 |= (fabsf(sB) > 2.0f) ? 1 : 0;
    }
    float f0 = 0.0f, f1 = 0.0f;
#pragma unroll
    for (int k = 0; k < 8; ++k) {
        if (k < nk) {                             // pad iterations contribute nothing
            f0 += (d0 < fx[k])     ? kv[k].x : -kv[k].x;
            f1 += (d0 + 1 < fx[k]) ? kv[k].y : -kv[k].y;
        }
    }

    const int col = dloc;
    s_meta[wave][col]     = (int)(sg0 >> 31) | (a30 << 8);
    s_meta[wave][col + 1] = (int)(sg1 >> 31) | (a31 << 8);
    s_f[wave][col]     = f0;
    s_f[wave][col + 1] = f1;
    __syncthreads();

    if (tid < DB) {
        int msum = 0;
        float f = 0.0f;
#pragma unroll
        for (int w2 = 0; w2 < NW; ++w2) {
            msum += s_meta[w2][tid];
            f    += s_f[w2][tid];                 // exact: sum of +-1 integers
        }
        bool neg  = (msum & 1) != 0;              // parity of sign bits
        bool any3 = (msum >> 8) != 0;             // any |x+y+z| == 3
        float o;
        if (f >= 0.0f) o = neg ? -1.0f : 1.0f;
        else           o = (neg && any3) ? 1.0f : -1.0f;
        out[blockIdx.x * DB + tid] = o;
    }
}

extern "C" void kernel_launch(void* const* d_in, const int* in_sizes, int n_in,
                              void* d_out, int out_size, void* d_ws, size_t ws_size,
                              hipStream_t stream) {
    const float* input = (const float*)d_in[0];
    const float* feat  = (const float*)d_in[1];
    const float* Wx    = (const float*)d_in[2];
    const float* Wy    = (const float*)d_in[3];
    const float* Wz    = (const float*)d_in[4];
    const float* Wt    = (const float*)d_in[5];
    const float* keys  = (const float*)d_in[6];
    float* out = (float*)d_out;

    dim3 grid(D_DIM / DB);   // 256 blocks -> one per CU
    dim3 block(TPB);
    hipLaunchKernelGGL(hdc_encode_kernel, grid, block, 0, stream,
                       input, feat, Wx, Wy, Wz, Wt, keys, out);
}